// Round 6
// baseline (449.049 us; speedup 1.0000x reference)
//
#include <hip/hip_runtime.h>

typedef unsigned int uint32;
typedef unsigned long long uint64;
typedef float floatx2 __attribute__((ext_vector_type(2)));
typedef uint32 u32x8 __attribute__((ext_vector_type(8)));

#define ROWS_R 2000
#define COLS_R 20000
#define NBLK   256
#define NTHR   1024
#define NWAVE  16
#define CPB    80          /* columns per block: 250 blocks cover 20000; 250..255 all-pad */
#define CSTR   502         /* LDS column stride in dwords (even => 8B-aligned b64 reads) */
#define KDW    (CPB*CSTR)  /* 40160 dwords = 160640 B */
#define KGUARD 16          /* zero guard so tail reads stay in-bounds */

static constexpr float A_MARG = 1.0f / 2000.0f;
static constexpr float B_MARG = 1.0f / 20000.0f;
static constexpr float EPSV   = 1e-16f;
static constexpr float THR    = 0.005f;
static constexpr float NALPHA = -20.0f;

// ---- agent-scope (device-coherent) access helpers: bypass the non-coherent L2 ----
// Writer drains vmcnt(0) (stores acked at coherence point) BEFORE the barrier
// arrival; reader loads only AFTER observing the generation flag.
__device__ __forceinline__ void st_dev_f32(float* p, float v) {
    __hip_atomic_store(p, v, __ATOMIC_RELAXED, __HIP_MEMORY_SCOPE_AGENT);
}
__device__ __forceinline__ float ld_dev_f32(const float* p) {
    return __hip_atomic_load(const_cast<float*>(p), __ATOMIC_RELAXED, __HIP_MEMORY_SCOPE_AGENT);
}
__device__ __forceinline__ void st_dev_f32x2(float* p, float x, float y) {
    union { float2 f; uint64 q; } u; u.f = make_float2(x, y);
    __hip_atomic_store(reinterpret_cast<uint64*>(p), u.q, __ATOMIC_RELAXED, __HIP_MEMORY_SCOPE_AGENT);
}
__device__ __forceinline__ float2 ld_dev_f32x2(const float* p) {
    union { float2 f; uint64 q; } u;
    u.q = __hip_atomic_load(reinterpret_cast<uint64*>(const_cast<float*>(p)),
                            __ATOMIC_RELAXED, __HIP_MEMORY_SCOPE_AGENT);
    return u.f;
}

// ---- cross-lane: sum of the two 32-lane halves, in every lane (VALU, off the DS pipe) ----
__device__ __forceinline__ float halfpair_sum(float x) {
#if __has_builtin(__builtin_amdgcn_permlane32_swap)
    int xi = __float_as_int(x);
    auto sw = __builtin_amdgcn_permlane32_swap(xi, xi, false, false);
    return __int_as_float(sw[0]) + __int_as_float(sw[1]);
#else
    return x + __shfl_xor(x, 32, 64);
#endif
}

// ======================= two-level grid barrier (fence-free, 1-hop wake) =======================
// ctrl dwords: [0]=root_cnt, [128+g*64]=group_cnt, [768+g*64]=group_gen.
// All cross-block DATA moves via agent-scope atomics, so no __threadfence
// (no L2 writeback/invalidate) is needed.
__device__ __forceinline__ void grid_barrier(uint32* ctrl, uint32 rnd) {
    asm volatile("s_waitcnt vmcnt(0)" ::: "memory");   // my stores are at the coherence point
    __syncthreads();
    if (threadIdx.x == 0) {
        const int gid = (int)(blockIdx.x >> 5);
        uint32* gcnt = ctrl + 128 + gid * 64;
        uint32* ggen = ctrl + 768 + gid * 64;
        uint32 a = __hip_atomic_fetch_add(gcnt, 1u, __ATOMIC_RELAXED, __HIP_MEMORY_SCOPE_AGENT);
        if (a == rnd * 32u + 31u) {
            uint32 r = __hip_atomic_fetch_add(ctrl, 1u, __ATOMIC_RELAXED, __HIP_MEMORY_SCOPE_AGENT);
            if (r == rnd * 8u + 7u) {
#pragma unroll
                for (int g = 0; g < 8; ++g)
                    __hip_atomic_store(ctrl + 768 + g * 64, rnd + 1u,
                                       __ATOMIC_RELAXED, __HIP_MEMORY_SCOPE_AGENT);
            }
        }
        while (__hip_atomic_load(ggen, __ATOMIC_RELAXED, __HIP_MEMORY_SCOPE_AGENT) < rnd + 1u)
            __builtin_amdgcn_s_sleep(1);
    }
    __syncthreads();
}

// ======================= init (ws is poisoned before every launch) =======================
__global__ __launch_bounds__(256) void init_kernel(float* __restrict__ u_g,
                                                   uint32* __restrict__ ctrl,
                                                   float* __restrict__ err2,
                                                   float* __restrict__ loss) {
    int idx = blockIdx.x * 256 + threadIdx.x;
    if (idx < 1280) ctrl[idx] = 0u;
    if (idx == 0) { err2[0] = 0.f; err2[1] = 0.f; *loss = 0.f; }
    if (idx < 2048) u_g[idx] = (idx < ROWS_R) ? A_MARG : 0.0f;   // zero pad rows!
}

// ======================= LDS-resident-K Sinkhorn, register-resident col slice ==============
// Block b owns columns [80b, 80b+80). K stripe lives in LDS (fp8, col-major) for
// the ROW pass (b64 reads); each wave pins its 5-column slice in NAMED ext_vector
// registers k0..k4 (no alloca -> no scratch demotion, the round-4/5 spill fix),
// so the COL pass does zero LDS reads. waves_per_eu(4,4): LDS caps us at 4
// waves/EU anyway; declaring it gives the allocator the full 128-VGPR budget.
__attribute__((amdgpu_waves_per_eu(4, 4)))
__global__ __launch_bounds__(NTHR) void sinkhorn_lds(
    const float* __restrict__ M,
    float* __restrict__ u_g,          // 2048 floats (pad rows = 0)
    float* __restrict__ P,            // 256 x 2048 floats
    uint32* __restrict__ ctrl,
    float* __restrict__ err2,
    float* __restrict__ loss,
    float* __restrict__ out) {
    __shared__ uint32 sK[KDW + KGUARD];   // ~160.6 KB
    __shared__ float  s_vloc[CPB];
    __shared__ float  s_vprev[CPB];
    __shared__ float  s_red[NWAVE * 8];
    __shared__ int    s_flag;

    const int tid  = threadIdx.x;
    const int lane = tid & 63;
    const int wav  = tid >> 6;
    const int b    = blockIdx.x;
    const int j0   = b * CPB;
    uint32 bar = 0;

    // ---------------- build: zero LDS, then pack exp(-20 M) fp8 col-major ----------------
    for (int i = tid; i < KDW + KGUARD; i += NTHR) sK[i] = 0u;
    __syncthreads();
    for (int q = wav; q < 500; q += NWAVE) {          // row-quad q -> rows 4q..4q+3
#pragma unroll
        for (int ph = 0; ph < 2; ++ph) {
            const int cl = ph * 64 + lane;            // local col 0..79
            const int j  = j0 + cl;
            if ((ph == 0 || lane < 16) && j < COLS_R) {
                const float* mp = M + (size_t)(4 * q) * COLS_R + j;
                float k0v = __expf(NALPHA * mp[0]);
                float k1v = __expf(NALPHA * mp[COLS_R]);
                float k2v = __expf(NALPHA * mp[2 * COLS_R]);
                float k3v = __expf(NALPHA * mp[3 * COLS_R]);
                int lo = __builtin_amdgcn_cvt_pk_fp8_f32(k0v, k1v, 0, false);
                int hi = __builtin_amdgcn_cvt_pk_fp8_f32(k2v, k3v, lo, true);
                sK[cl * CSTR + q] = (uint32)hi;       // dword = rows 4q..4q+3 of col cl
            }
        }
    }
    __syncthreads();

    // ---- pin this wave's col-pass slice in NAMED vector registers (spill-proof).
    //      Lane holds quads {s*64+lane} of cols wav*5..wav*5+4; quads >= 500 read
    //      pad/next-col garbage which multiplies zero u rows (u pad = 0). ----
    u32x8 k0, k1, k2, k3, k4;
    {
        auto fill = [&](int q) {
            u32x8 r;
#pragma unroll
            for (int s = 0; s < 8; ++s)
                r[s] = sK[(wav * 5 + q) * CSTR + s * 64 + lane];
            return r;
        };
        k0 = fill(0); k1 = fill(1); k2 = fill(2); k3 = fill(3); k4 = fill(4);
    }

    // ---------------- Sinkhorn loop ----------------
    for (int t = 1; t <= 100; ++t) {
        // err check folded: iter t's col pass computes K^T u_{t-1} (= err input at cpt=t-1)
        const bool chk  = (t == 2) || (t == 52);
        const int  slot = (t == 52) ? 1 : 0;

        // preload u(t-1): issue all 16 8-B loads, one latency wait
        float4 u_r[8];
#pragma unroll
        for (int s = 0; s < 8; ++s) {
            const float* up = u_g + (size_t)(s * 64 + lane) * 4;
            float2 a0 = ld_dev_f32x2(up);
            float2 a1 = ld_dev_f32x2(up + 2);
            u_r[s] = make_float4(a0.x, a0.y, a1.x, a1.y);
        }

        // col pass: pure-register MACs (zero LDS); wave owns cols wav*5..wav*5+4
        auto colq = [&](u32x8 kv) {
            float a = 0.f;
#pragma unroll
            for (int s = 0; s < 8; ++s) {
                uint32 kw = kv[s];
                floatx2 f01 = __builtin_amdgcn_cvt_pk_f32_fp8(kw, false);
                floatx2 f23 = __builtin_amdgcn_cvt_pk_f32_fp8(kw, true);
                a += f01.x * u_r[s].x + f01.y * u_r[s].y
                   + f23.x * u_r[s].z + f23.y * u_r[s].w;
            }
            return a;
        };
        float acc[5] = { colq(k0), colq(k1), colq(k2), colq(k3), colq(k4) };

        float e = 0.f;
#pragma unroll
        for (int q = 0; q < 5; ++q) {
            const int jl = wav * 5 + q;
            float a = acc[q];
            a = halfpair_sum(a);                      // 64 -> 32 on the VALU pipe
#pragma unroll
            for (int o = 16; o; o >>= 1) a += __shfl_xor(a, o, 64);
            if (lane == 0) {
                float vnew = B_MARG / (a + EPSV);
                if (chk) {
                    float vold = s_vloc[jl];
                    s_vprev[jl] = vold;               // preserve v_{t-1} for break/loss
                    if (j0 + jl < COLS_R) e += fabsf(vold * a - B_MARG);
                }
                s_vloc[jl] = vnew;
            }
        }
        if (chk && lane == 0) s_red[wav] = e;
        __syncthreads();                              // v_local ready

        // row partials (b64): lane reads 2 quads (8 rows) of col cl = jp*4 + (lane>>4),
        // quads w*32 + 2*(lane&15). 20 ds_read_b64 + 20 vloc reads vs old 40+40 b32.
        {
            const int rg = lane >> 4;                 // column subgroup 0..3
            const int rm = lane & 15;                 // row-octet index
            const int qbase = wav * 32 + 2 * rm;
            float4 pb0 = make_float4(0.f, 0.f, 0.f, 0.f);
            float4 pb1 = make_float4(0.f, 0.f, 0.f, 0.f);
#pragma unroll 4
            for (int jp = 0; jp < 20; ++jp) {
                const int cl = jp * 4 + rg;
                uint2 kw2 = *reinterpret_cast<const uint2*>(&sK[cl * CSTR + qbase]);
                float vv = s_vloc[cl];
                floatx2 a01 = __builtin_amdgcn_cvt_pk_f32_fp8(kw2.x, false);
                floatx2 a23 = __builtin_amdgcn_cvt_pk_f32_fp8(kw2.x, true);
                floatx2 b01 = __builtin_amdgcn_cvt_pk_f32_fp8(kw2.y, false);
                floatx2 b23 = __builtin_amdgcn_cvt_pk_f32_fp8(kw2.y, true);
                pb0.x += a01.x * vv; pb0.y += a01.y * vv;
                pb0.z += a23.x * vv; pb0.w += a23.y * vv;
                pb1.x += b01.x * vv; pb1.y += b01.y * vv;
                pb1.z += b23.x * vv; pb1.w += b23.y * vv;
            }
            // reduce across the 4 column subgroups: lanes stride 16 (xor16), then 32-swap
            pb0.x += __shfl_xor(pb0.x, 16, 64);  pb0.y += __shfl_xor(pb0.y, 16, 64);
            pb0.z += __shfl_xor(pb0.z, 16, 64);  pb0.w += __shfl_xor(pb0.w, 16, 64);
            pb1.x += __shfl_xor(pb1.x, 16, 64);  pb1.y += __shfl_xor(pb1.y, 16, 64);
            pb1.z += __shfl_xor(pb1.z, 16, 64);  pb1.w += __shfl_xor(pb1.w, 16, 64);
            pb0.x = halfpair_sum(pb0.x);  pb0.y = halfpair_sum(pb0.y);
            pb0.z = halfpair_sum(pb0.z);  pb0.w = halfpair_sum(pb0.w);
            pb1.x = halfpair_sum(pb1.x);  pb1.y = halfpair_sum(pb1.y);
            pb1.z = halfpair_sum(pb1.z);  pb1.w = halfpair_sum(pb1.w);
            if (lane < 16) {                          // rows w*128 + 8*lane .. +7
                float* dst = P + (size_t)b * 2048 + wav * 128 + 8 * lane;
                st_dev_f32x2(dst,     pb0.x, pb0.y);
                st_dev_f32x2(dst + 2, pb0.z, pb0.w);
                st_dev_f32x2(dst + 4, pb1.x, pb1.y);
                st_dev_f32x2(dst + 6, pb1.z, pb1.w);
            }
        }

        if (chk && tid == 0) {
            float s = 0.f;
            for (int k = 0; k < NWAVE; ++k) s += s_red[k];
            if (s != 0.f) atomicAdd(&err2[slot], s);
        }
        grid_barrier(ctrl, bar++);

        if (chk) {
            if (tid == 0) s_flag = (ld_dev_f32(&err2[slot]) <= THR) ? 1 : 0;
            __syncthreads();
            if (s_flag) {                             // converged at cpt=t-1
                if (tid < CPB) s_vloc[tid] = s_vprev[tid];   // restore v_{t-1} for loss
                __syncthreads();
                break;                                // u_g still holds u_{t-1}
            }
        }

        // finalize u: block b owns rows 8b..8b+7; reduce 256 partials per row
        {
            float v0 = ld_dev_f32(P + (size_t)(tid >> 3) * 2048 + 8 * b + (tid & 7));
            float v1 = ld_dev_f32(P + (size_t)((tid >> 3) + 128) * 2048 + 8 * b + (tid & 7));
            float s = v0 + v1;
            s += __shfl_xor(s, 8, 64);
            s += __shfl_xor(s, 16, 64);
            s = halfpair_sum(s);
            if (lane < 8) s_red[wav * 8 + lane] = s;  // row slot = lane
        }
        __syncthreads();
        if (tid < 8) {
            float s = 0.f;
            for (int w = 0; w < NWAVE; ++w) s += s_red[w * 8 + tid];
            const int row = 8 * b + tid;
            float val = (row < ROWS_R) ? A_MARG / (s + EPSV) : 0.0f;  // keep pad zero!
            st_dev_f32(&u_g[row], val);
        }
        grid_barrier(ctrl, bar++);
    }

    // ---------------- loss = sum_ij u_i exp(-20 M_ij) v_j M_ij (fp32 from M) ----------------
    {
        float acc = 0.f;
        for (int r = wav; r < ROWS_R; r += NWAVE) {
            const float uu = ld_dev_f32(&u_g[r]);     // wave-uniform scalar
            const float* mp = M + (size_t)r * COLS_R + j0;
#pragma unroll
            for (int ph = 0; ph < 2; ++ph) {
                const int cl = ph * 64 + lane;
                if ((ph == 0 || lane < 16) && (j0 + cl) < COLS_R) {
                    float m = mp[cl];
                    acc += uu * __expf(NALPHA * m) * s_vloc[cl] * m;
                }
            }
        }
        acc = halfpair_sum(acc);
#pragma unroll
        for (int o = 16; o; o >>= 1) acc += __shfl_xor(acc, o, 64);
        if (lane == 0) s_red[wav] = acc;
        __syncthreads();
        if (tid == 0) {
            float s = 0.f;
            for (int k = 0; k < NWAVE; ++k) s += s_red[k];
            if (s != 0.f) atomicAdd(loss, s);
        }
    }
    grid_barrier(ctrl, bar++);
    if (b == 0 && tid == 0) out[0] = ld_dev_f32(loss) * 100.0f;
}

// ======================= fallback path (tiny workspace) =======================

__device__ __forceinline__ float block_reduce_sum256(float v) {
#pragma unroll
    for (int o = 32; o; o >>= 1) v += __shfl_down(v, o, 64);
    __shared__ float smem[4];
    int lane = threadIdx.x & 63, w = threadIdx.x >> 6;
    if (lane == 0) smem[w] = v;
    __syncthreads();
    v = (threadIdx.x < 4) ? smem[threadIdx.x] : 0.0f;
    v += __shfl_down(v, 2, 64);
    v += __shfl_down(v, 1, 64);
    return v;
}

__global__ __launch_bounds__(256) void fb_init(float* u, float* vden, int* done, float* err, float* loss) {
    int idx = blockIdx.x * 256 + threadIdx.x;
    if (idx == 0) { *done = 0; *err = 0.0f; *loss = 0.0f; }
    if (idx < ROWS_R) u[idx] = A_MARG;
    if (idx < COLS_R) vden[idx] = 0.0f;
}
__global__ __launch_bounds__(256) void fb_colpass(const float* __restrict__ M, const float* __restrict__ u,
                                                  float* __restrict__ vden, const int* __restrict__ done) {
    if (*done) return;
    int c4 = blockIdx.x * 256 + threadIdx.x;
    if (c4 >= 5000) return;
    int r0 = blockIdx.y * 50;
    float4 acc = make_float4(0.f, 0.f, 0.f, 0.f);
    for (int r = r0; r < r0 + 50; ++r) {
        float ui = u[r];
        float4 mm = reinterpret_cast<const float4*>(M)[(size_t)r * 5000 + c4];
        acc.x += __expf(NALPHA * mm.x) * ui; acc.y += __expf(NALPHA * mm.y) * ui;
        acc.z += __expf(NALPHA * mm.z) * ui; acc.w += __expf(NALPHA * mm.w) * ui;
    }
    atomicAdd(&vden[c4 * 4 + 0], acc.x); atomicAdd(&vden[c4 * 4 + 1], acc.y);
    atomicAdd(&vden[c4 * 4 + 2], acc.z); atomicAdd(&vden[c4 * 4 + 3], acc.w);
}
__global__ __launch_bounds__(256) void fb_finv(float* v, float* vden, const int* done) {
    if (*done) return;
    int j = blockIdx.x * 256 + threadIdx.x;
    if (j < COLS_R) { v[j] = B_MARG / (vden[j] + EPSV); vden[j] = 0.0f; }
}
__global__ __launch_bounds__(256) void fb_rowpass(const float* __restrict__ M, const float* __restrict__ v,
                                                  float* __restrict__ u, const int* __restrict__ done) {
    if (*done) return;
    int row = blockIdx.x;
    const float4* v4 = reinterpret_cast<const float4*>(v);
    float acc = 0.0f;
    for (int c4 = threadIdx.x; c4 < 5000; c4 += 256) {
        float4 mm = reinterpret_cast<const float4*>(M)[(size_t)row * 5000 + c4];
        float4 vv = v4[c4];
        acc += __expf(NALPHA * mm.x) * vv.x + __expf(NALPHA * mm.y) * vv.y
             + __expf(NALPHA * mm.z) * vv.z + __expf(NALPHA * mm.w) * vv.w;
    }
    float s = block_reduce_sum256(acc);
    if (threadIdx.x == 0) u[row] = A_MARG / (s + EPSV);
}
__global__ __launch_bounds__(256) void fb_errfin(const float* v, float* vden, float* err, const int* done) {
    if (*done) return;
    int j = blockIdx.x * 256 + threadIdx.x;
    float local = 0.0f;
    if (j < COLS_R) { local = fabsf(v[j] * vden[j] - B_MARG); vden[j] = 0.0f; }
    float s = block_reduce_sum256(local);
    if (threadIdx.x == 0) atomicAdd(err, s);
}
__global__ void fb_check(int* done, float* err) {
    if (threadIdx.x == 0) { if (!*done && *err <= THR) *done = 1; *err = 0.0f; }
}
__global__ __launch_bounds__(256) void fb_loss(const float* __restrict__ M, const float* __restrict__ u,
                                               const float* __restrict__ v, float* __restrict__ loss) {
    int row = blockIdx.x;
    const float4* M4p = reinterpret_cast<const float4*>(M + (size_t)row * COLS_R);
    const float4* v4 = reinterpret_cast<const float4*>(v);
    float acc = 0.0f;
    for (int c4 = threadIdx.x; c4 < 5000; c4 += 256) {
        float4 mm = M4p[c4]; float4 vv = v4[c4];
        acc += __expf(NALPHA * mm.x) * vv.x * mm.x + __expf(NALPHA * mm.y) * vv.y * mm.y
             + __expf(NALPHA * mm.z) * vv.z * mm.z + __expf(NALPHA * mm.w) * vv.w * mm.w;
    }
    float s = block_reduce_sum256(acc);
    if (threadIdx.x == 0) atomicAdd(loss, s * u[row]);
}
__global__ void fb_writeout(float* out, const float* loss) {
    if (threadIdx.x == 0) out[0] = *loss * 100.0f;
}

// ======================= host launch =======================

extern "C" void kernel_launch(void* const* d_in, const int* in_sizes, int n_in,
                              void* d_out, int out_size, void* d_ws, size_t ws_size,
                              hipStream_t stream) {
    const float* M = (const float*)d_in[0];
    char* base = (char*)d_ws;

    const size_t OFF_CTRL = 0;                        // uint32[2048] (8 KB; 1280 used)
    const size_t OFF_ERR  = 8192;
    const size_t OFF_LOSS = 8320;
    const size_t OFF_U    = 8448;                     // 2048 floats (16B aligned)
    const size_t OFF_P    = OFF_U + 8192 + 256;       // 256 x 2048 floats
    const size_t NEED     = OFF_P + (size_t)NBLK * 2048 * 4;   // ~2.1 MB

    if (ws_size >= NEED) {
        uint32* ctrl = (uint32*)(base + OFF_CTRL);
        float*  err2 = (float*)(base + OFF_ERR);
        float*  loss = (float*)(base + OFF_LOSS);
        float*  u_g  = (float*)(base + OFF_U);
        float*  P    = (float*)(base + OFF_P);

        init_kernel<<<8, 256, 0, stream>>>(u_g, ctrl, err2, loss);
        sinkhorn_lds<<<NBLK, NTHR, 0, stream>>>(M, u_g, P, ctrl, err2, loss, (float*)d_out);
    } else {
        int*   done = (int*)(base + 0);
        float* err  = (float*)(base + 8);
        float* loss = (float*)(base + 16);
        float* u    = (float*)(base + 64);
        float* v    = (float*)(base + 64 + 8192);
        float* vden = (float*)(base + 64 + 8192 + 80000);

        fb_init<<<79, 256, 0, stream>>>(u, vden, done, err, loss);
        dim3 cgrid(20, 40);
        for (int t = 1; t <= 100; ++t) {
            fb_colpass<<<cgrid, 256, 0, stream>>>(M, u, vden, done);
            fb_finv<<<79, 256, 0, stream>>>(v, vden, done);
            fb_rowpass<<<ROWS_R, 256, 0, stream>>>(M, v, u, done);
            if (t == 1 || t == 51) {
                fb_colpass<<<cgrid, 256, 0, stream>>>(M, u, vden, done);
                fb_errfin<<<79, 256, 0, stream>>>(v, vden, err, done);
                fb_check<<<1, 64, 0, stream>>>(done, err);
            }
        }
        fb_loss<<<ROWS_R, 256, 0, stream>>>(M, u, v, loss);
        fb_writeout<<<1, 64, 0, stream>>>((float*)d_out, loss);
    }
}

// Round 7
// 329.207 us; speedup vs baseline: 1.3640x; 1.3640x over previous
//
#include <hip/hip_runtime.h>

typedef unsigned int uint32;
typedef unsigned long long uint64;
typedef float floatx2 __attribute__((ext_vector_type(2)));

#define ROWS_R 2000
#define COLS_R 20000
#define NBLK   256
#define NTHR   1024
#define NWAVE  16
#define CPB    80          /* columns per block: 250 blocks cover 20000; 250..255 all-pad */
#define CSTR   501         /* LDS column stride in dwords (2004 B): 500 data + 1 zero pad */
#define KDW    (CPB*CSTR)  /* 40080 dwords = 160320 B */
#define KGUARD 16          /* zero guard so col-pass tail reads (d<=511) stay in-bounds */
#define USLOTS 101         /* rotating u buffers: slot t = u(t); never re-read a stale line */

static constexpr float A_MARG = 1.0f / 2000.0f;
static constexpr float B_MARG = 1.0f / 20000.0f;
static constexpr float EPSV   = 1e-16f;
static constexpr float THR    = 0.005f;
static constexpr float NALPHA = -20.0f;

// ---- agent-scope (device-coherent) access helpers: bypass the non-coherent L2 ----
// Writer drains vmcnt(0) (stores acked at coherence point) BEFORE the barrier
// arrival; reader loads only AFTER observing the generation flag.
// u READS deliberately do NOT use these: u(t) lives in a write-once rotating slot,
// so plain cached loads are safe (a reader's L2 line for slot t is first filled
// AFTER the barrier that ordered all slot-t writes) and get XCD-level reuse:
// per-XCD u traffic drops 4 MB/iter -> 8 KB/iter.
__device__ __forceinline__ void st_dev_f32(float* p, float v) {
    __hip_atomic_store(p, v, __ATOMIC_RELAXED, __HIP_MEMORY_SCOPE_AGENT);
}
__device__ __forceinline__ float ld_dev_f32(const float* p) {
    return __hip_atomic_load(const_cast<float*>(p), __ATOMIC_RELAXED, __HIP_MEMORY_SCOPE_AGENT);
}
__device__ __forceinline__ void st_dev_f32x2(float* p, float x, float y) {
    union { float2 f; uint64 q; } u; u.f = make_float2(x, y);
    __hip_atomic_store(reinterpret_cast<uint64*>(p), u.q, __ATOMIC_RELAXED, __HIP_MEMORY_SCOPE_AGENT);
}
__device__ __forceinline__ float2 ld_dev_f32x2(const float* p) {
    union { float2 f; uint64 q; } u;
    u.q = __hip_atomic_load(reinterpret_cast<uint64*>(const_cast<float*>(p)),
                            __ATOMIC_RELAXED, __HIP_MEMORY_SCOPE_AGENT);
    return u.f;
}

// ---- cross-lane: sum of the two 32-lane halves, in every lane (VALU, off the DS pipe) ----
__device__ __forceinline__ float halfpair_sum(float x) {
#if __has_builtin(__builtin_amdgcn_permlane32_swap)
    int xi = __float_as_int(x);
    auto sw = __builtin_amdgcn_permlane32_swap(xi, xi, false, false);
    return __int_as_float(sw[0]) + __int_as_float(sw[1]);
#else
    return x + __shfl_xor(x, 32, 64);
#endif
}

// ======================= two-level grid barrier (fence-free, 1-hop wake) =======================
// ctrl dwords: [0]=root_cnt, [128+g*64]=group_cnt, [768+g*64]=group_gen.
// Cross-block DATA moves via agent-scope atomics or write-once cached buffers,
// so no __threadfence (no L2 writeback/invalidate) is needed.
__device__ __forceinline__ void grid_barrier(uint32* ctrl, uint32 rnd) {
    asm volatile("s_waitcnt vmcnt(0)" ::: "memory");   // my stores are at the coherence point
    __syncthreads();
    if (threadIdx.x == 0) {
        const int gid = (int)(blockIdx.x >> 5);
        uint32* gcnt = ctrl + 128 + gid * 64;
        uint32* ggen = ctrl + 768 + gid * 64;
        uint32 a = __hip_atomic_fetch_add(gcnt, 1u, __ATOMIC_RELAXED, __HIP_MEMORY_SCOPE_AGENT);
        if (a == rnd * 32u + 31u) {
            uint32 r = __hip_atomic_fetch_add(ctrl, 1u, __ATOMIC_RELAXED, __HIP_MEMORY_SCOPE_AGENT);
            if (r == rnd * 8u + 7u) {
#pragma unroll
                for (int g = 0; g < 8; ++g)
                    __hip_atomic_store(ctrl + 768 + g * 64, rnd + 1u,
                                       __ATOMIC_RELAXED, __HIP_MEMORY_SCOPE_AGENT);
            }
        }
        while (__hip_atomic_load(ggen, __ATOMIC_RELAXED, __HIP_MEMORY_SCOPE_AGENT) < rnd + 1u)
            __builtin_amdgcn_s_sleep(1);
    }
    __syncthreads();
}

// ======================= init (ws is poisoned before every launch) =======================
// u slot 0 = u(0); kernel-boundary release makes these plain stores visible to the
// main dispatch. Slots 1..100 are fully written (all 2048 rows) before first read.
__global__ __launch_bounds__(256) void init_kernel(float* __restrict__ u_rot,
                                                   uint32* __restrict__ ctrl,
                                                   float* __restrict__ err2,
                                                   float* __restrict__ loss) {
    int idx = blockIdx.x * 256 + threadIdx.x;
    if (idx < 1280) ctrl[idx] = 0u;
    if (idx == 0) { err2[0] = 0.f; err2[1] = 0.f; *loss = 0.f; }
    if (idx < 2048) u_rot[idx] = (idx < ROWS_R) ? A_MARG : 0.0f;   // zero pad rows!
}

// ======================= LDS-resident-K Sinkhorn, rotating cached u =======================
// Block b owns columns [80b, 80b+80). K stripe lives in LDS (fp8, col-major,
// stride 2004 B). v is block-local. Cross-block exchange: P partials + u.
// u(t) is written (agent stores) into rotating slot t and read with PLAIN cached
// loads -> each 8 KB slot is fetched from LLC once per XCD instead of once per
// wave (the ~32 MB/iter LLC broadcast that bounded rounds 0-3).
__global__ __launch_bounds__(NTHR, 1) void sinkhorn_lds(
    const float* __restrict__ M,
    float* __restrict__ u_rot,        // USLOTS x 2048 floats (pad rows = 0)
    float* __restrict__ P,            // 256 x 2048 floats
    uint32* __restrict__ ctrl,
    float* __restrict__ err2,
    float* __restrict__ loss,
    float* __restrict__ out) {
    __shared__ uint32 sK[KDW + KGUARD];   // ~160.4 KB
    __shared__ float  s_vloc[CPB];
    __shared__ float  s_vprev[CPB];
    __shared__ float  s_red[NWAVE * 8];
    __shared__ int    s_flag;

    const int tid  = threadIdx.x;
    const int lane = tid & 63;
    const int wav  = tid >> 6;
    const int b    = blockIdx.x;
    const int j0   = b * CPB;
    uint32 bar = 0;

    // ---------------- build: zero LDS, then pack exp(-20 M) fp8 col-major ----------------
    for (int i = tid; i < KDW + KGUARD; i += NTHR) sK[i] = 0u;
    __syncthreads();
    for (int q = wav; q < 500; q += NWAVE) {          // row-quad q -> rows 4q..4q+3
#pragma unroll
        for (int ph = 0; ph < 2; ++ph) {
            const int cl = ph * 64 + lane;            // local col 0..79
            const int j  = j0 + cl;
            if ((ph == 0 || lane < 16) && j < COLS_R) {
                const float* mp = M + (size_t)(4 * q) * COLS_R + j;
                float k0 = __expf(NALPHA * mp[0]);
                float k1 = __expf(NALPHA * mp[COLS_R]);
                float k2 = __expf(NALPHA * mp[2 * COLS_R]);
                float k3 = __expf(NALPHA * mp[3 * COLS_R]);
                int lo = __builtin_amdgcn_cvt_pk_fp8_f32(k0, k1, 0, false);
                int hi = __builtin_amdgcn_cvt_pk_fp8_f32(k2, k3, lo, true);
                sK[cl * CSTR + q] = (uint32)hi;       // dword = rows 4q..4q+3 of col cl
            }
        }
    }
    __syncthreads();

    // ---------------- Sinkhorn loop ----------------
    int usel = 0;   // current u slot (u(t-1) at top of iteration t)

    for (int t = 1; t <= 100; ++t) {
        // err check folded: iter t's col pass computes K^T u_{t-1} (= err input at cpt=t-1)
        const bool chk  = (t == 2) || (t == 52);
        const int  slot = (t == 52) ? 1 : 0;

        // preload u(t-1): PLAIN cached float4 loads from write-once slot (L2-shared per XCD)
        const float4* u4 = reinterpret_cast<const float4*>(u_rot + (size_t)usel * 2048);
        float4 u_r[8];
#pragma unroll
        for (int s = 0; s < 8; ++s) u_r[s] = u4[s * 64 + lane];

        // col pass: wave handles 5 of the 80 local columns
        float e = 0.f;
#pragma unroll
        for (int q = 0; q < 5; ++q) {
            const int jl = wav * 5 + q;
            float acc = 0.f;
#pragma unroll
            for (int s = 0; s < 8; ++s) {             // d up to 511: pad/guard are zero, u pad = 0
                uint32 kw = sK[jl * CSTR + s * 64 + lane];
                floatx2 f01 = __builtin_amdgcn_cvt_pk_f32_fp8(kw, false);
                floatx2 f23 = __builtin_amdgcn_cvt_pk_f32_fp8(kw, true);
                acc += f01.x * u_r[s].x + f01.y * u_r[s].y + f23.x * u_r[s].z + f23.y * u_r[s].w;
            }
            acc = halfpair_sum(acc);                  // 64 -> 32 on the VALU pipe
#pragma unroll
            for (int o = 16; o; o >>= 1) acc += __shfl_xor(acc, o, 64);
            if (lane == 0) {
                float vnew = B_MARG / (acc + EPSV);
                if (chk) {
                    float vold = s_vloc[jl];
                    s_vprev[jl] = vold;               // preserve v_{t-1} for break/loss
                    if (j0 + jl < COLS_R) e += fabsf(vold * acc - B_MARG);
                }
                s_vloc[jl] = vnew;
            }
        }
        if (chk && lane == 0) s_red[wav] = e;
        __syncthreads();                              // v_local ready

        // row partials: wave w owns rows w*128..w*128+127; iterate col pairs
        float4 pa = make_float4(0.f, 0.f, 0.f, 0.f);
#pragma unroll 8
        for (int jp = 0; jp < 40; ++jp) {
            const int cl = 2 * jp + (lane >> 5);
            const int m  = lane & 31;
            uint32 kw = sK[cl * CSTR + wav * 32 + m]; // rows w*128+4m..+3
            float  vv = s_vloc[cl];
            floatx2 f01 = __builtin_amdgcn_cvt_pk_f32_fp8(kw, false);
            floatx2 f23 = __builtin_amdgcn_cvt_pk_f32_fp8(kw, true);
            pa.x += f01.x * vv; pa.y += f01.y * vv;
            pa.z += f23.x * vv; pa.w += f23.y * vv;
        }
        pa.x = halfpair_sum(pa.x);
        pa.y = halfpair_sum(pa.y);
        pa.z = halfpair_sum(pa.z);
        pa.w = halfpair_sum(pa.w);
        if (lane < 32) {
            float* dst = P + (size_t)b * 2048 + wav * 128 + 4 * lane;
            st_dev_f32x2(dst,     pa.x, pa.y);
            st_dev_f32x2(dst + 2, pa.z, pa.w);
        }

        if (chk && tid == 0) {
            float s = 0.f;
            for (int k = 0; k < NWAVE; ++k) s += s_red[k];
            if (s != 0.f) atomicAdd(&err2[slot], s);
        }
        grid_barrier(ctrl, bar++);

        if (chk) {
            if (tid == 0) s_flag = (ld_dev_f32(&err2[slot]) <= THR) ? 1 : 0;
            __syncthreads();
            if (s_flag) {                             // converged at cpt=t-1
                if (tid < CPB) s_vloc[tid] = s_vprev[tid];   // restore v_{t-1} for loss
                __syncthreads();
                break;                                // usel still = t-1 slot
            }
        }

        // finalize u: block b owns rows 8b..8b+7; reduce 256 partials per row,
        // write u(t) into rotating slot t (agent stores -> LLC before barrier)
        {
            float v0 = ld_dev_f32(P + (size_t)(tid >> 3) * 2048 + 8 * b + (tid & 7));
            float v1 = ld_dev_f32(P + (size_t)((tid >> 3) + 128) * 2048 + 8 * b + (tid & 7));
            float s = v0 + v1;
            s += __shfl_xor(s, 8, 64);
            s += __shfl_xor(s, 16, 64);
            s = halfpair_sum(s);
            if (lane < 8) s_red[wav * 8 + lane] = s;  // row slot = lane
        }
        __syncthreads();
        if (tid < 8) {
            float s = 0.f;
            for (int w = 0; w < NWAVE; ++w) s += s_red[w * 8 + tid];
            const int row = 8 * b + tid;
            float val = (row < ROWS_R) ? A_MARG / (s + EPSV) : 0.0f;  // keep pad zero!
            st_dev_f32(u_rot + (size_t)t * 2048 + row, val);
        }
        usel = t;
        grid_barrier(ctrl, bar++);
    }

    // ---------------- loss = sum_ij u_i exp(-20 M_ij) v_j M_ij (fp32 from M) ----------------
    {
        const float* uf = u_rot + (size_t)usel * 2048;   // final u slot (cached reads safe)
        float acc = 0.f;
        for (int r = wav; r < ROWS_R; r += NWAVE) {
            const float uu = uf[r];                   // wave-uniform scalar
            const float* mp = M + (size_t)r * COLS_R + j0;
#pragma unroll
            for (int ph = 0; ph < 2; ++ph) {
                const int cl = ph * 64 + lane;
                if ((ph == 0 || lane < 16) && (j0 + cl) < COLS_R) {
                    float m = mp[cl];
                    acc += uu * __expf(NALPHA * m) * s_vloc[cl] * m;
                }
            }
        }
        acc = halfpair_sum(acc);
#pragma unroll
        for (int o = 16; o; o >>= 1) acc += __shfl_xor(acc, o, 64);
        if (lane == 0) s_red[wav] = acc;
        __syncthreads();
        if (tid == 0) {
            float s = 0.f;
            for (int k = 0; k < NWAVE; ++k) s += s_red[k];
            if (s != 0.f) atomicAdd(loss, s);
        }
    }
    grid_barrier(ctrl, bar++);
    if (b == 0 && tid == 0) out[0] = ld_dev_f32(loss) * 100.0f;
}

// ======================= fallback path (tiny workspace) =======================

__device__ __forceinline__ float block_reduce_sum256(float v) {
#pragma unroll
    for (int o = 32; o; o >>= 1) v += __shfl_down(v, o, 64);
    __shared__ float smem[4];
    int lane = threadIdx.x & 63, w = threadIdx.x >> 6;
    if (lane == 0) smem[w] = v;
    __syncthreads();
    v = (threadIdx.x < 4) ? smem[threadIdx.x] : 0.0f;
    v += __shfl_down(v, 2, 64);
    v += __shfl_down(v, 1, 64);
    return v;
}

__global__ __launch_bounds__(256) void fb_init(float* u, float* vden, int* done, float* err, float* loss) {
    int idx = blockIdx.x * 256 + threadIdx.x;
    if (idx == 0) { *done = 0; *err = 0.0f; *loss = 0.0f; }
    if (idx < ROWS_R) u[idx] = A_MARG;
    if (idx < COLS_R) vden[idx] = 0.0f;
}
__global__ __launch_bounds__(256) void fb_colpass(const float* __restrict__ M, const float* __restrict__ u,
                                                  float* __restrict__ vden, const int* __restrict__ done) {
    if (*done) return;
    int c4 = blockIdx.x * 256 + threadIdx.x;
    if (c4 >= 5000) return;
    int r0 = blockIdx.y * 50;
    float4 acc = make_float4(0.f, 0.f, 0.f, 0.f);
    for (int r = r0; r < r0 + 50; ++r) {
        float ui = u[r];
        float4 mm = reinterpret_cast<const float4*>(M)[(size_t)r * 5000 + c4];
        acc.x += __expf(NALPHA * mm.x) * ui; acc.y += __expf(NALPHA * mm.y) * ui;
        acc.z += __expf(NALPHA * mm.z) * ui; acc.w += __expf(NALPHA * mm.w) * ui;
    }
    atomicAdd(&vden[c4 * 4 + 0], acc.x); atomicAdd(&vden[c4 * 4 + 1], acc.y);
    atomicAdd(&vden[c4 * 4 + 2], acc.z); atomicAdd(&vden[c4 * 4 + 3], acc.w);
}
__global__ __launch_bounds__(256) void fb_finv(float* v, float* vden, const int* done) {
    if (*done) return;
    int j = blockIdx.x * 256 + threadIdx.x;
    if (j < COLS_R) { v[j] = B_MARG / (vden[j] + EPSV); vden[j] = 0.0f; }
}
__global__ __launch_bounds__(256) void fb_rowpass(const float* __restrict__ M, const float* __restrict__ v,
                                                  float* __restrict__ u, const int* __restrict__ done) {
    if (*done) return;
    int row = blockIdx.x;
    const float4* v4 = reinterpret_cast<const float4*>(v);
    float acc = 0.0f;
    for (int c4 = threadIdx.x; c4 < 5000; c4 += 256) {
        float4 mm = reinterpret_cast<const float4*>(M)[(size_t)row * 5000 + c4];
        float4 vv = v4[c4];
        acc += __expf(NALPHA * mm.x) * vv.x + __expf(NALPHA * mm.y) * vv.y
             + __expf(NALPHA * mm.z) * vv.z + __expf(NALPHA * mm.w) * vv.w;
    }
    float s = block_reduce_sum256(acc);
    if (threadIdx.x == 0) u[row] = A_MARG / (s + EPSV);
}
__global__ __launch_bounds__(256) void fb_errfin(const float* v, float* vden, float* err, const int* done) {
    if (*done) return;
    int j = blockIdx.x * 256 + threadIdx.x;
    float local = 0.0f;
    if (j < COLS_R) { local = fabsf(v[j] * vden[j] - B_MARG); vden[j] = 0.0f; }
    float s = block_reduce_sum256(local);
    if (threadIdx.x == 0) atomicAdd(err, s);
}
__global__ void fb_check(int* done, float* err) {
    if (threadIdx.x == 0) { if (!*done && *err <= THR) *done = 1; *err = 0.0f; }
}
__global__ __launch_bounds__(256) void fb_loss(const float* __restrict__ M, const float* __restrict__ u,
                                               const float* __restrict__ v, float* __restrict__ loss) {
    int row = blockIdx.x;
    const float4* M4p = reinterpret_cast<const float4*>(M + (size_t)row * COLS_R);
    const float4* v4 = reinterpret_cast<const float4*>(v);
    float acc = 0.0f;
    for (int c4 = threadIdx.x; c4 < 5000; c4 += 256) {
        float4 mm = M4p[c4]; float4 vv = v4[c4];
        acc += __expf(NALPHA * mm.x) * vv.x * mm.x + __expf(NALPHA * mm.y) * vv.y * mm.y
             + __expf(NALPHA * mm.z) * vv.z * mm.z + __expf(NALPHA * mm.w) * vv.w * mm.w;
    }
    float s = block_reduce_sum256(acc);
    if (threadIdx.x == 0) atomicAdd(loss, s * u[row]);
}
__global__ void fb_writeout(float* out, const float* loss) {
    if (threadIdx.x == 0) out[0] = *loss * 100.0f;
}

// ======================= host launch =======================

extern "C" void kernel_launch(void* const* d_in, const int* in_sizes, int n_in,
                              void* d_out, int out_size, void* d_ws, size_t ws_size,
                              hipStream_t stream) {
    const float* M = (const float*)d_in[0];
    char* base = (char*)d_ws;

    const size_t OFF_CTRL = 0;                        // uint32[2048] (8 KB; 1280 used)
    const size_t OFF_ERR  = 8192;
    const size_t OFF_LOSS = 8320;
    const size_t OFF_UROT = 8448;                     // USLOTS x 2048 floats (16B aligned)
    const size_t OFF_P    = OFF_UROT + (size_t)USLOTS * 2048 * 4;   // 256 x 2048 floats
    const size_t NEED     = OFF_P + (size_t)NBLK * 2048 * 4;        // ~2.93 MB

    if (ws_size >= NEED) {
        uint32* ctrl  = (uint32*)(base + OFF_CTRL);
        float*  err2  = (float*)(base + OFF_ERR);
        float*  loss  = (float*)(base + OFF_LOSS);
        float*  u_rot = (float*)(base + OFF_UROT);
        float*  P     = (float*)(base + OFF_P);

        init_kernel<<<8, 256, 0, stream>>>(u_rot, ctrl, err2, loss);
        sinkhorn_lds<<<NBLK, NTHR, 0, stream>>>(M, u_rot, P, ctrl, err2, loss, (float*)d_out);
    } else {
        int*   done = (int*)(base + 0);
        float* err  = (float*)(base + 8);
        float* loss = (float*)(base + 16);
        float* u    = (float*)(base + 64);
        float* v    = (float*)(base + 64 + 8192);
        float* vden = (float*)(base + 64 + 8192 + 80000);

        fb_init<<<79, 256, 0, stream>>>(u, vden, done, err, loss);
        dim3 cgrid(20, 40);
        for (int t = 1; t <= 100; ++t) {
            fb_colpass<<<cgrid, 256, 0, stream>>>(M, u, vden, done);
            fb_finv<<<79, 256, 0, stream>>>(v, vden, done);
            fb_rowpass<<<ROWS_R, 256, 0, stream>>>(M, v, u, done);
            if (t == 1 || t == 51) {
                fb_colpass<<<cgrid, 256, 0, stream>>>(M, u, vden, done);
                fb_errfin<<<79, 256, 0, stream>>>(v, vden, err, done);
                fb_check<<<1, 64, 0, stream>>>(done, err);
            }
        }
        fb_loss<<<ROWS_R, 256, 0, stream>>>(M, u, v, loss);
        fb_writeout<<<1, 64, 0, stream>>>((float*)d_out, loss);
    }
}